// Round 1
// baseline (1424.522 us; speedup 1.0000x reference)
//
#include <hip/hip_runtime.h>

typedef unsigned short u16;
typedef __attribute__((ext_vector_type(8))) short short8;
typedef __attribute__((ext_vector_type(4))) float f32x4;

#define NTOK 8192
#define HD   1024
#define NE   8
#define ID   4096
#define BM   128
#define BN   128
#define BK   32

__device__ __forceinline__ u16 f2bf(float f) {
  unsigned u = __builtin_bit_cast(unsigned, f);
  u += 0x7FFFu + ((u >> 16) & 1u);
  return (u16)(u >> 16);
}

__device__ __forceinline__ void gld16(const void* g, void* l) {
  __builtin_amdgcn_global_load_lds((const __attribute__((address_space(1))) void*)g,
                                   (__attribute__((address_space(3))) void*)l, 16, 0, 0);
}

// ---------------- conversion kernels ----------------
__global__ __launch_bounds__(256) void convert_x_kernel(const float* __restrict__ in,
                                                        u16* __restrict__ out) {
  int i = (blockIdx.x * 256 + threadIdx.x) * 4;
  float4 v = *(const float4*)(in + i);
  ushort4 o;
  o.x = f2bf(v.x); o.y = f2bf(v.y); o.z = f2bf(v.z); o.w = f2bf(v.w);
  *(ushort4*)(out + i) = o;
}

// in: [z][R][C] f32  ->  out: [z][C][R] bf16
__global__ __launch_bounds__(256) void transpose_kernel(const float* __restrict__ in,
                                                        u16* __restrict__ out,
                                                        int R, int C) {
  __shared__ float tile[32][33];
  const size_t mat = (size_t)R * C;
  const float* inp = in + blockIdx.z * mat;
  u16* outp = out + blockIdx.z * mat;
  int c0 = blockIdx.x * 32, r0 = blockIdx.y * 32;
  int tx = threadIdx.x & 31, ty = threadIdx.x >> 5;  // 32x8
#pragma unroll
  for (int j = 0; j < 4; ++j)
    tile[ty + j * 8][tx] = inp[(size_t)(r0 + ty + j * 8) * C + (c0 + tx)];
  __syncthreads();
#pragma unroll
  for (int j = 0; j < 4; ++j)
    outp[(size_t)(c0 + ty + j * 8) * R + (r0 + tx)] = f2bf(tile[tx][ty + j * 8]);
}

// ---------------- gating ----------------
__global__ __launch_bounds__(256) void gate_kernel(const float* __restrict__ x,
                                                   const float* __restrict__ gw,
                                                   int* __restrict__ top_idx,
                                                   float* __restrict__ top_w,
                                                   int* __restrict__ counts) {
  int t = blockIdx.x * 4 + (threadIdx.x >> 6);
  int lane = threadIdx.x & 63;
  const float* xr = x + (size_t)t * HD;
  float p[NE];
#pragma unroll
  for (int e = 0; e < NE; ++e) p[e] = 0.f;
  for (int i = 0; i < HD / 64; ++i) {
    int h = i * 64 + lane;
    float xv = xr[h];
    const float* g = gw + (size_t)h * NE;
#pragma unroll
    for (int e = 0; e < NE; ++e) p[e] += xv * g[e];
  }
#pragma unroll
  for (int e = 0; e < NE; ++e) {
    float v = p[e];
    v += __shfl_xor(v, 32); v += __shfl_xor(v, 16); v += __shfl_xor(v, 8);
    v += __shfl_xor(v, 4);  v += __shfl_xor(v, 2);  v += __shfl_xor(v, 1);
    p[e] = v;
  }
  if (lane == 0) {
    float m = p[0];
#pragma unroll
    for (int e = 1; e < NE; ++e) m = fmaxf(m, p[e]);
    float q[NE];
#pragma unroll
    for (int e = 0; e < NE; ++e) q[e] = expf(p[e] - m);
    int e0 = 0; float b0 = q[0];
#pragma unroll
    for (int e = 1; e < NE; ++e) if (q[e] > b0) { b0 = q[e]; e0 = e; }
    int e1 = (e0 == 0) ? 1 : 0; float b1 = q[e1];
#pragma unroll
    for (int e = 0; e < NE; ++e) if (e != e0 && q[e] > b1) { b1 = q[e]; e1 = e; }
    float inv = 1.f / (b0 + b1);
    top_idx[2 * t] = e0; top_idx[2 * t + 1] = e1;
    top_w[2 * t] = b0 * inv; top_w[2 * t + 1] = b1 * inv;
    atomicAdd(&counts[e0], 1);
    atomicAdd(&counts[e1], 1);
  }
}

__global__ void offsets_kernel(const int* __restrict__ counts, int* __restrict__ offsets,
                               int* __restrict__ cursor) {
  if (threadIdx.x == 0) {
    int acc = 0;
    for (int e = 0; e < NE; ++e) { offsets[e] = acc; acc += counts[e]; cursor[e] = 0; }
    offsets[NE] = acc;
  }
}

__global__ __launch_bounds__(256) void scatter_kernel(const int* __restrict__ top_idx,
                                                      const float* __restrict__ top_w,
                                                      const int* __restrict__ offsets,
                                                      int* __restrict__ cursor,
                                                      int* __restrict__ perm_token,
                                                      float* __restrict__ perm_w) {
  int t = blockIdx.x * 256 + threadIdx.x;
  if (t >= NTOK) return;
#pragma unroll
  for (int k = 0; k < 2; ++k) {
    int e = top_idx[2 * t + k];
    int pos = atomicAdd(&cursor[e], 1);
    int slot = offsets[e] + pos;
    perm_token[slot] = t;
    perm_w[slot] = top_w[2 * t + k];
  }
}

// ---------------- GEMM1: Hbuf = silu(Xg @ w1) * (Xg @ w3), bf16 out ----------------
__global__ __launch_bounds__(256, 2) void gemm1_kernel(const u16* __restrict__ Xbf,
                                                       const u16* __restrict__ W1t,
                                                       const u16* __restrict__ W3t,
                                                       u16* __restrict__ Hbuf,
                                                       const int* __restrict__ perm_token,
                                                       const int* __restrict__ offsets) {
  const int e = blockIdx.z;
  const int off0 = offsets[e], off1 = offsets[e + 1];
  const int m0 = off0 + blockIdx.y * BM;
  if (m0 >= off1) return;
  const int n0 = blockIdx.x * BN;

  __shared__ __align__(16) u16 As[2][BM * BK];
  __shared__ __align__(16) u16 B1s[2][BN * BK];
  __shared__ __align__(16) u16 B3s[2][BN * BK];

  const int tid = threadIdx.x;
  const int lane = tid & 63, w = tid >> 6;
  const int wm = w >> 1, wn = w & 1;
  const int kcol = (lane & 3) * 8;     // elem offset in K within tile row
  const int g0 = w * 2;
  const int rsub = lane >> 2;          // row within 16-row group

  const u16* aSrc[2]; const u16* b1Src[2]; const u16* b3Src[2];
#pragma unroll
  for (int j = 0; j < 2; ++j) {
    int r = (g0 + j) * 16 + rsub;
    int slot = m0 + r; if (slot > off1 - 1) slot = off1 - 1;
    int tok = perm_token[slot];
    aSrc[j] = Xbf + (size_t)tok * HD + kcol;
    size_t woff = ((size_t)e * ID + n0 + r) * HD + kcol;
    b1Src[j] = W1t + woff;
    b3Src[j] = W3t + woff;
  }

  f32x4 acc1[4][4] = {};
  f32x4 acc3[4][4] = {};

  auto STAGE = [&](int buf, int kt) {
#pragma unroll
    for (int j = 0; j < 2; ++j) {
      gld16(aSrc[j] + kt * BK, &As[buf][(g0 + j) * 512]);
      gld16(b1Src[j] + kt * BK, &B1s[buf][(g0 + j) * 512]);
      gld16(b3Src[j] + kt * BK, &B3s[buf][(g0 + j) * 512]);
    }
  };

  STAGE(0, 0);
  __syncthreads();
  int cur = 0;
  const int KT = HD / BK;  // 32
  for (int kt = 0; kt < KT; ++kt) {
    if (kt + 1 < KT) STAGE(cur ^ 1, kt + 1);
    const int krd = 8 * (lane >> 4);
    short8 af[4], b1f[4], b3f[4];
#pragma unroll
    for (int mf = 0; mf < 4; ++mf)
      af[mf] = *(const short8*)&As[cur][(wm * 64 + mf * 16 + (lane & 15)) * BK + krd];
#pragma unroll
    for (int nf = 0; nf < 4; ++nf) {
      int n = (wn * 64 + nf * 16 + (lane & 15)) * BK + krd;
      b1f[nf] = *(const short8*)&B1s[cur][n];
      b3f[nf] = *(const short8*)&B3s[cur][n];
    }
#pragma unroll
    for (int mf = 0; mf < 4; ++mf)
#pragma unroll
      for (int nf = 0; nf < 4; ++nf) {
        acc1[mf][nf] = __builtin_amdgcn_mfma_f32_16x16x32_bf16(af[mf], b1f[nf], acc1[mf][nf], 0, 0, 0);
        acc3[mf][nf] = __builtin_amdgcn_mfma_f32_16x16x32_bf16(af[mf], b3f[nf], acc3[mf][nf], 0, 0, 0);
      }
    __syncthreads();
    cur ^= 1;
  }

#pragma unroll
  for (int mf = 0; mf < 4; ++mf) {
#pragma unroll
    for (int j = 0; j < 4; ++j) {
      int slot = m0 + wm * 64 + mf * 16 + (lane >> 4) * 4 + j;
      if (slot < off1) {
#pragma unroll
        for (int nf = 0; nf < 4; ++nf) {
          int c = n0 + wn * 64 + nf * 16 + (lane & 15);
          float v1 = acc1[mf][nf][j];
          float v3 = acc3[mf][nf][j];
          float h = v1 / (1.f + __expf(-v1)) * v3;
          Hbuf[(size_t)slot * ID + c] = f2bf(h);
        }
      }
    }
  }
}

// ---------------- GEMM2: out[token] += (Hbuf @ w2) * w ----------------
__global__ __launch_bounds__(256, 2) void gemm2_kernel(const u16* __restrict__ Hbuf,
                                                       const u16* __restrict__ W2t,
                                                       float* __restrict__ out,
                                                       const int* __restrict__ perm_token,
                                                       const float* __restrict__ perm_w,
                                                       const int* __restrict__ offsets) {
  const int e = blockIdx.z;
  const int off0 = offsets[e], off1 = offsets[e + 1];
  const int m0 = off0 + blockIdx.y * BM;
  if (m0 >= off1) return;
  const int n0 = blockIdx.x * BN;

  __shared__ __align__(16) u16 As[2][BM * BK];
  __shared__ __align__(16) u16 Bs[2][BN * BK];

  const int tid = threadIdx.x;
  const int lane = tid & 63, w = tid >> 6;
  const int wm = w >> 1, wn = w & 1;
  const int kcol = (lane & 3) * 8;
  const int g0 = w * 2;
  const int rsub = lane >> 2;

  const u16* aSrc[2]; const u16* bSrc[2];
#pragma unroll
  for (int j = 0; j < 2; ++j) {
    int r = (g0 + j) * 16 + rsub;
    int slot = m0 + r; if (slot > off1 - 1) slot = off1 - 1;
    aSrc[j] = Hbuf + (size_t)slot * ID + kcol;
    bSrc[j] = W2t + ((size_t)e * HD + n0 + r) * ID + kcol;
  }

  f32x4 acc[4][4] = {};

  auto STAGE = [&](int buf, int kt) {
#pragma unroll
    for (int j = 0; j < 2; ++j) {
      gld16(aSrc[j] + kt * BK, &As[buf][(g0 + j) * 512]);
      gld16(bSrc[j] + kt * BK, &Bs[buf][(g0 + j) * 512]);
    }
  };

  STAGE(0, 0);
  __syncthreads();
  int cur = 0;
  const int KT = ID / BK;  // 128
  for (int kt = 0; kt < KT; ++kt) {
    if (kt + 1 < KT) STAGE(cur ^ 1, kt + 1);
    const int krd = 8 * (lane >> 4);
    short8 af[4], bf[4];
#pragma unroll
    for (int mf = 0; mf < 4; ++mf)
      af[mf] = *(const short8*)&As[cur][(wm * 64 + mf * 16 + (lane & 15)) * BK + krd];
#pragma unroll
    for (int nf = 0; nf < 4; ++nf)
      bf[nf] = *(const short8*)&Bs[cur][(wn * 64 + nf * 16 + (lane & 15)) * BK + krd];
#pragma unroll
    for (int mf = 0; mf < 4; ++mf)
#pragma unroll
      for (int nf = 0; nf < 4; ++nf)
        acc[mf][nf] = __builtin_amdgcn_mfma_f32_16x16x32_bf16(af[mf], bf[nf], acc[mf][nf], 0, 0, 0);
    __syncthreads();
    cur ^= 1;
  }

#pragma unroll
  for (int mf = 0; mf < 4; ++mf) {
#pragma unroll
    for (int j = 0; j < 4; ++j) {
      int slot = m0 + wm * 64 + mf * 16 + (lane >> 4) * 4 + j;
      if (slot < off1) {
        int t = perm_token[slot];
        float wt = perm_w[slot];
#pragma unroll
        for (int nf = 0; nf < 4; ++nf) {
          int c = n0 + wn * 64 + nf * 16 + (lane & 15);
          atomicAdd(&out[(size_t)t * HD + c], acc[mf][nf][j] * wt);
        }
      }
    }
  }
}

extern "C" void kernel_launch(void* const* d_in, const int* in_sizes, int n_in,
                              void* d_out, int out_size, void* d_ws, size_t ws_size,
                              hipStream_t stream) {
  const float* x  = (const float*)d_in[0];  // [4,2048,1024]
  const float* gw = (const float*)d_in[1];  // [1024,8]
  const float* w1 = (const float*)d_in[2];  // [8,1024,4096]
  const float* w3 = (const float*)d_in[3];  // [8,1024,4096]
  const float* w2 = (const float*)d_in[4];  // [8,4096,1024]
  float* out = (float*)d_out;

  char* p = (char*)d_ws;
  u16* Xbf = (u16*)p;  p += (size_t)NTOK * HD * 2;          // 16.8 MB
  u16* W1t = (u16*)p;  p += (size_t)NE * HD * ID * 2;       // 67.1 MB
  u16* W3t = (u16*)p;  p += (size_t)NE * HD * ID * 2;       // 67.1 MB
  u16* W2t = (u16*)p;  p += (size_t)NE * HD * ID * 2;       // 67.1 MB
  u16* Hbuf = (u16*)p; p += (size_t)NTOK * 2 * ID * 2;      // 134.2 MB
  int* top_idx = (int*)p;    p += (size_t)NTOK * 2 * 4;
  float* top_w = (float*)p;  p += (size_t)NTOK * 2 * 4;
  int* counts = (int*)p;     p += 128;
  int* offs = (int*)p;       p += 128;
  int* cursor = (int*)p;     p += 128;
  int* perm_token = (int*)p; p += (size_t)NTOK * 2 * 4;
  float* perm_w = (float*)p; p += (size_t)NTOK * 2 * 4;
  // total ws use ~353 MB

  hipMemsetAsync(out, 0, (size_t)NTOK * HD * 4, stream);
  hipMemsetAsync(counts, 0, 128, stream);

  convert_x_kernel<<<NTOK * HD / (256 * 4), 256, 0, stream>>>(x, Xbf);
  transpose_kernel<<<dim3(ID / 32, HD / 32, NE), 256, 0, stream>>>(w1, W1t, HD, ID);
  transpose_kernel<<<dim3(ID / 32, HD / 32, NE), 256, 0, stream>>>(w3, W3t, HD, ID);
  transpose_kernel<<<dim3(HD / 32, ID / 32, NE), 256, 0, stream>>>(w2, W2t, ID, HD);
  gate_kernel<<<NTOK / 4, 256, 0, stream>>>(x, gw, top_idx, top_w, counts);
  offsets_kernel<<<1, 64, 0, stream>>>(counts, offs, cursor);
  scatter_kernel<<<NTOK / 256, 256, 0, stream>>>(top_idx, top_w, offs, cursor, perm_token, perm_w);
  gemm1_kernel<<<dim3(ID / BN, 64, NE), 256, 0, stream>>>(Xbf, W1t, W3t, Hbuf, perm_token, offs);
  gemm2_kernel<<<dim3(HD / BN, 64, NE), 256, 0, stream>>>(Hbuf, W2t, out, perm_token, perm_w, offs);
}